// Round 10
// baseline (278.375 us; speedup 1.0000x reference)
//
#include <hip/hip_runtime.h>
#include <math.h>
#include <float.h>

#define N_NODES 1024
#define IN_CH   1433
#define HID     16
#define OUT_CH  7
#define N_EDGES 4096
#define E_TOT   5120   // N_EDGES + N_NODES (self loops)
#define N_TE    5119   // embedded series length (valid sorted slots 0..5118)
#define SP      5120   // pitch for per-channel sorted arrays

// psi(x) for integer-valued x >= 1. Recurrence to x>=6 then asymptotic.
// digammaf_dev(0) = -inf, matching jax digamma(0) for the degenerate eps==0 case.
__device__ __forceinline__ float digammaf_dev(float x) {
    float r = 0.0f;
    while (x < 6.0f) { r -= 1.0f / x; x += 1.0f; }
    float inv  = 1.0f / x;
    float inv2 = inv * inv;
    r += logf(x) - 0.5f * inv
       - inv2 * (1.0f/12.0f - inv2 * (1.0f/120.0f - inv2 * (1.0f/252.0f)));
    return r;
}

// h1[r][o] = sum_k x[r][k] * W1[o][k] + b1[o].  One block per row.
// Fused: degree count (cdeg) + src multiplicity (srcCnt): 5 edges per block.
__global__ __launch_bounds__(256) void gemm1_kernel(
    const float* __restrict__ x, const float* __restrict__ W1,
    const float* __restrict__ b1, const int* __restrict__ ei,
    float* __restrict__ h1, float* __restrict__ cdeg, int* __restrict__ srcCnt) {
    __shared__ float xrow[IN_CH];
    const int r = blockIdx.x;
    if (threadIdx.x < 5) {            // E_TOT = 5 * N_NODES exactly
        int e = r * 5 + threadIdx.x;
        int d = (e < N_EDGES) ? ei[N_EDGES + e] : (e - N_EDGES);
        atomicAdd(&cdeg[d], 1.0f);
        if (e < N_TE) {
            int s = (e < N_EDGES) ? ei[e] : (e - N_EDGES);
            atomicAdd(&srcCnt[s], 1);
        }
    }
    const float* xr = x + (size_t)r * IN_CH;
    for (int k = threadIdx.x; k < IN_CH; k += 256) xrow[k] = xr[k];
    __syncthreads();
    const int o = threadIdx.x >> 4;
    const int g = threadIdx.x & 15;
    const float* w = W1 + o * IN_CH;
    float s = 0.0f;
    for (int k = g; k < IN_CH; k += 16) s += xrow[k] * w[k];
    #pragma unroll
    for (int m = 8; m >= 1; m >>= 1) s += __shfl_xor(s, m, 16);
    if (g == 0) h1[r * HID + o] = s + b1[o];
}

// Per channel c (one block, 512 threads): bitonic-sort the 1024 node values
// (key=float as sortable uint, payload=node idx); rank/cursor/value tables in
// LDS; then counting-sort scatter of the 5119 embedded points into their
// y-sorted slots. Order inside equal-y groups arbitrary (results
// order-independent: min and window membership are y-value-determined).
// FUSE=false: values come from h[:, c] (layer 1).
// FUSE=true:  values are computed in-block as layer-2 pre-activations
//             h2[v][c] = b2[c] + sum_k relu(sums1[v][k]/deg) * W2[c][k]
//             (byte-identical float expressions to the old fin1gemm2),
//             and also written to h2out for the agg step.
template <int C, bool FUSE>
__global__ __launch_bounds__(512) void sortfill_kernel(
    const float* __restrict__ hin, const int* __restrict__ srcCnt,
    const int* __restrict__ ei,
    const float* __restrict__ sums1, const float* __restrict__ cdeg,
    const float* __restrict__ W2, const float* __restrict__ b2,
    float* __restrict__ h2out,
    float* __restrict__ xs, float* __restrict__ ys, float* __restrict__ zs) {
    __shared__ unsigned long long a[N_NODES];
    __shared__ float hv[N_NODES];
    __shared__ int rankL[N_NODES];
    __shared__ int curL[N_NODES];
    __shared__ int wsum[8];
    const int c = blockIdx.x;
    const int tid = threadIdx.x;
    for (int v = tid; v < N_NODES; v += 512) {
        float f;
        if constexpr (FUSE) {
            float invc = 1.0f / fmaxf(cdeg[v], 1.0f);
            float s = b2[c];
            #pragma unroll
            for (int k = 0; k < HID; ++k)
                s += fmaxf(sums1[v * HID + k] * invc, 0.0f) * W2[c * HID + k];
            f = s;
            h2out[v * C + c] = s;
        } else {
            f = hin[v * C + c];
        }
        hv[v] = f;
        unsigned u = __float_as_uint(f);
        u ^= (u & 0x80000000u) ? 0xFFFFFFFFu : 0x80000000u;
        a[v] = ((unsigned long long)u << 32) | (unsigned)v;
    }
    __syncthreads();
    for (int k = 2; k <= N_NODES; k <<= 1) {
        for (int j = k >> 1; j >= 1; j >>= 1) {
            {   // 512 threads <-> 512 compare-exchanges per substage
                int s = tid;
                int i  = ((s & ~(j - 1)) << 1) | (s & (j - 1));
                int p2 = i | j;
                unsigned long long A = a[i], B = a[p2];
                bool up = ((i & k) == 0);
                if ((A > B) == up) { a[i] = B; a[p2] = A; }
            }
            __syncthreads();
        }
    }
    // ranks + exclusive prefix sum of src multiplicities in sorted order
    const int r0 = tid * 2;
    int n0 = (int)(a[r0]     & 0xFFFFFFFFu);
    int n1 = (int)(a[r0 + 1] & 0xFFFFFFFFu);
    rankL[n0] = r0;
    rankL[n1] = r0 + 1;
    int c0 = srcCnt[n0], c1 = srcCnt[n1];
    int seg = c0 + c1;
    int run = seg;
    const int lane = tid & 63, wid = tid >> 6;
    #pragma unroll
    for (int m = 1; m < 64; m <<= 1) {
        int v = __shfl_up(run, m, 64);
        if (lane >= m) run += v;
    }
    if (lane == 63) wsum[wid] = run;
    __syncthreads();
    int base = 0;
    for (int ww = 0; ww < wid; ++ww) base += wsum[ww];
    int excl = base + run - seg;
    curL[r0]     = excl;
    curL[r0 + 1] = excl + c0;
    __syncthreads();
    // counting-sort scatter (cursor atomics in LDS; h values from LDS)
    for (int t = tid; t < N_TE; t += 512) {
        int s  = (t < N_EDGES)     ? ei[t]     : t - N_EDGES;
        int sn = (t + 1 < N_EDGES) ? ei[t + 1] : t + 1 - N_EDGES;
        int d  = (t < N_EDGES) ? ei[N_EDGES + t] : t - N_EDGES;
        int pos = atomicAdd(&curL[rankL[s]], 1);
        ys[c * SP + pos] = hv[s];
        xs[c * SP + pos] = hv[d];
        zs[c * SP + pos] = hv[sn];
    }
}

// Fused KSG: ONE 64-lane wave per point p (sorted position). Grid =
// nb blocks/channel; block (c, b_local) owns {p = i*nb + b_local} — stride-nb
// interleave decorrelates heavy-window clustering. Waves pull i from an LDS
// cursor (r8 lesson: a global cursor serializes the machine). Loop bodies
// identical to r7 (r6 lesson: perturbing the load pattern costs LDS
// conflicts).
//   eps phase:   break when ANY lane has dyB >= best_l — exactly the wave-min
//                stop, optimal exact. Overshoot-safe (d >= |dy|).
//   left loops:  pre-tested on the candidate round's top y.
//   count phase: ballot+popcount, counts in SGPRs; right scan owns the base
//                round, left scan strictly below; self pair IS the
//                +1-inside-psi convention; eps<=0 -> counts 0 -> digamma(0)
//                = -inf, matching the reference degenerate case.
// NEW: agg fused into the LAST block per channel (done[c] counter, one atomic
// per block): after all nb blocks contributed to tes[c], the last block reads
// tes[c] coherently (threadfence + atomicAdd(.,0)) and performs the per-edge
// sigmoid/segment-sum for its channel — removes the standalone agg dispatch
// and overlaps agg with other channels' te tails.
template <int C>
__global__ __launch_bounds__(1024, 4) void te_kernel(
    const float* __restrict__ xs, const float* __restrict__ ys,
    const float* __restrict__ zs,
    const float* __restrict__ h, const int* __restrict__ ei,
    float half_scale, float* __restrict__ tes,
    float* __restrict__ sums, int* __restrict__ done) {
    constexpr int LOFF = 512;            // left pad
    constexpr int LSZ  = 5888;           // LOFF + SP + 256 (covers prefetch)
    __shared__ __align__(16) float Xs[LSZ];
    __shared__ __align__(16) float Ys[LSZ];
    __shared__ __align__(16) float Zs[LSZ];
    __shared__ int lcur;
    __shared__ int lastflag;
    const int nb = gridDim.x / C;        // blocks per channel
    const int c = blockIdx.x / nb;
    const int b_local = blockIdx.x % nb;
    const int tid = threadIdx.x;
    {
        const float4* gx4 = (const float4*)(xs + (size_t)c * SP);
        const float4* gy4 = (const float4*)(ys + (size_t)c * SP);
        const float4* gz4 = (const float4*)(zs + (size_t)c * SP);
        float4* lx4 = (float4*)(Xs + LOFF);
        float4* ly4 = (float4*)(Ys + LOFF);
        float4* lz4 = (float4*)(Zs + LOFF);
        for (int t = tid; t < SP / 4; t += 1024) {
            lx4[t] = gx4[t]; ly4[t] = gy4[t]; lz4[t] = gz4[t];
        }
        for (int t = tid; t < LOFF; t += 1024) {
            Xs[t] = -FLT_MAX; Ys[t] = -FLT_MAX; Zs[t] = -FLT_MAX;
        }
        for (int t = LOFF + SP + tid; t < LSZ; t += 1024) {
            Xs[t] = FLT_MAX; Ys[t] = FLT_MAX; Zs[t] = FLT_MAX;
        }
    }
    __syncthreads();
    if (tid == 0) {  // slot N_TE holds fill garbage; make it a sentinel
        Xs[LOFF + N_TE] = FLT_MAX; Ys[LOFF + N_TE] = FLT_MAX; Zs[LOFF + N_TE] = FLT_MAX;
        lcur = 0;
    }
    __syncthreads();

    const int wv = tid >> 6, l = tid & 63;
    float accum = 0.0f;

#define LD4(arr, idx) (*(const float4*)((arr) + LOFF + (idx)))
#define TE_D(xc, yc, zc) \
    fmaxf(fmaxf(fabsf((xc) - xi), fabsf((yc) - yi)), fabsf((zc) - zi))

    while (true) {
        int i = 0;
        if (l == 0) i = atomicAdd(&lcur, 1);
        i = __shfl(i, 0, 64);
        const int p = i * nb + b_local;
        if (p >= N_TE) break;

        const float xi = Xs[LOFF + p], yi = Ys[LOFF + p], zi = Zs[LOFF + p];
        const int base = p & ~255;
        const int lo4 = l * 4;

        float best = FLT_MAX;
        // ---- eps: right/up (includes base round; j==p masked; prefetched) --
        {
            int b = base;
            float4 x0 = LD4(Xs, b + lo4), y0 = LD4(Ys, b + lo4), z0 = LD4(Zs, b + lo4);
            float yB0 = Ys[LOFF + b + 255];
            while (true) {
                float4 x1 = LD4(Xs, b + 256 + lo4);
                float4 y1 = LD4(Ys, b + 256 + lo4);
                float4 z1 = LD4(Zs, b + 256 + lo4);
                float yB1 = Ys[LOFF + b + 511];
                const int j0 = b + lo4;
                float d0 = TE_D(x0.x, y0.x, z0.x);
                float d1 = TE_D(x0.y, y0.y, z0.y);
                float d2 = TE_D(x0.z, y0.z, z0.z);
                float d3 = TE_D(x0.w, y0.w, z0.w);
                d0 = (j0     == p) ? FLT_MAX : d0;
                d1 = (j0 + 1 == p) ? FLT_MAX : d1;
                d2 = (j0 + 2 == p) ? FLT_MAX : d2;
                d3 = (j0 + 3 == p) ? FLT_MAX : d3;
                best = fminf(fminf(best, d0), fminf(fminf(d1, d2), d3));
                if (__ballot(yB0 - yi >= best) != 0ull) break;   // wave-min stop
                x0 = x1; y0 = y1; z0 = z1; yB0 = yB1; b += 256;
            }
        }
        // ---- eps: left/down, pre-tested on candidate round's top y ----
        {
            int b = base - 256;
            while (__ballot(yi - Ys[LOFF + b + 255] >= best) == 0ull) {
                float4 x0 = LD4(Xs, b + lo4), y0 = LD4(Ys, b + lo4), z0 = LD4(Zs, b + lo4);
                float d0 = TE_D(x0.x, y0.x, z0.x);
                float d1 = TE_D(x0.y, y0.y, z0.y);
                float d2 = TE_D(x0.z, y0.z, z0.z);
                float d3 = TE_D(x0.w, y0.w, z0.w);
                best = fminf(fminf(best, d0), fminf(fminf(d1, d2), d3));
                b -= 256;
            }
        }
        #pragma unroll
        for (int m = 1; m < 64; m <<= 1) best = fminf(best, __shfl_xor(best, m, 64));
        const float eps = best;

        int ny = 0, nxy = 0, nyz = 0;
        if (eps > 0.0f) {
#define TE_CSLOT(xc, yc, zc)                                                 \
    {                                                                        \
        unsigned long long my_ = __ballot(fabsf((yc) - yi) < eps);           \
        unsigned long long mx_ = __ballot(fabsf((xc) - xi) < eps);           \
        unsigned long long mz_ = __ballot(fabsf((zc) - zi) < eps);           \
        ny  += __popcll(my_);                                                \
        nxy += __popcll(my_ & mx_);                                          \
        nyz += __popcll(my_ & mz_);                                          \
    }
            // ---- count: right (whole base round + up; self included) ----
            {
                int b = base;
                float4 x0 = LD4(Xs, b + lo4), y0 = LD4(Ys, b + lo4), z0 = LD4(Zs, b + lo4);
                float yB0 = Ys[LOFF + b + 255];
                while (true) {
                    float4 x1 = LD4(Xs, b + 256 + lo4);
                    float4 y1 = LD4(Ys, b + 256 + lo4);
                    float4 z1 = LD4(Zs, b + 256 + lo4);
                    float yB1 = Ys[LOFF + b + 511];
                    TE_CSLOT(x0.x, y0.x, z0.x)
                    TE_CSLOT(x0.y, y0.y, z0.y)
                    TE_CSLOT(x0.z, y0.z, z0.z)
                    TE_CSLOT(x0.w, y0.w, z0.w)
                    if (yB0 - yi >= eps) break;      // uniform: window covered
                    x0 = x1; y0 = y1; z0 = z1; yB0 = yB1; b += 256;
                }
            }
            // ---- count: left, pre-tested on candidate round's top y ----
            {
                int b = base - 256;
                while (yi - Ys[LOFF + b + 255] < eps) {   // uniform
                    float4 x0 = LD4(Xs, b + lo4), y0 = LD4(Ys, b + lo4), z0 = LD4(Zs, b + lo4);
                    TE_CSLOT(x0.x, y0.x, z0.x)
                    TE_CSLOT(x0.y, y0.y, z0.y)
                    TE_CSLOT(x0.z, y0.z, z0.z)
                    TE_CSLOT(x0.w, y0.w, z0.w)
                    b -= 256;
                }
            }
#undef TE_CSLOT
        }
        if (l == 0)
            accum += digammaf_dev((float)ny) - digammaf_dev((float)nxy)
                   - digammaf_dev((float)nyz);
    }
#undef LD4
#undef TE_D

    __shared__ float wred[16];
    if (l == 0) wred[wv] = accum;
    __syncthreads();
    if (tid == 0) {
        float s = 0.0f;
        #pragma unroll
        for (int i = 0; i < 16; ++i) s += wred[i];
        atomicAdd(&tes[c], s);
        __threadfence();                       // release our tes add
        int old = atomicAdd(&done[c], 1);
        lastflag = (old == nb - 1) ? 1 : 0;
    }
    __syncthreads();
    if (lastflag) {
        // last block for channel c: all nb tes-adds happened-before their
        // done-increments; acquire and read the full sum coherently.
        __threadfence();
        float tsum = atomicAdd(&tes[c], 0.0f);
        float te = (-0.57721566490153286f + tsum * (1.0f / (float)N_TE)) * half_scale;
        for (int e = tid; e < E_TOT; e += 1024) {
            int s_ = (e < N_EDGES) ? ei[e] : (e - N_EDGES);
            int d_ = (e < N_EDGES) ? ei[N_EDGES + e] : (e - N_EDGES);
            float xj = h[s_ * C + c];
            float m = 1.0f / (1.0f + expf(-te * xj));
            atomicAdd(&sums[d_ * C + c], m);
        }
    }
}

__global__ void fin2_kernel(const float* __restrict__ sums2, const float* __restrict__ cnt,
                            float* __restrict__ out) {
    int v = blockIdx.x * blockDim.x + threadIdx.x;
    if (v >= N_NODES) return;
    float c = fmaxf(cnt[v], 1.0f);
    float vals[OUT_CH];
    float mx = -INFINITY;
    #pragma unroll
    for (int o = 0; o < OUT_CH; ++o) {
        vals[o] = sums2[v * OUT_CH + o] / c;
        mx = fmaxf(mx, vals[o]);
    }
    float se = 0.0f;
    #pragma unroll
    for (int o = 0; o < OUT_CH; ++o) se += expf(vals[o] - mx);
    float lse = mx + logf(se);
    #pragma unroll
    for (int o = 0; o < OUT_CH; ++o) out[v * OUT_CH + o] = vals[o] - lse;
}

extern "C" void kernel_launch(void* const* d_in, const int* in_sizes, int n_in,
                              void* d_out, int out_size, void* d_ws, size_t ws_size,
                              hipStream_t stream) {
    const float* x  = (const float*)d_in[0];
    const int*   ei = (const int*)  d_in[1];
    const float* W1 = (const float*)d_in[2];
    const float* b1 = (const float*)d_in[3];
    const float* W2 = (const float*)d_in[4];
    const float* b2 = (const float*)d_in[5];
    float* out = (float*)d_out;

    float* w = (float*)d_ws;
    size_t o = 0;
    // ---- zeroed region (atomic accumulators) ----
    float* sums1 = w + o; o += N_NODES * HID;      // 16384
    float* sums2 = w + o; o += N_NODES * OUT_CH;   // 7168
    float* cdeg  = w + o; o += N_NODES;            // 1024
    float* tes1  = w + o; o += 16;
    float* tes2  = w + o; o += 16;
    int* srcCnt  = (int*)(w + o); o += N_NODES;    // 1024 ints
    int* done1   = (int*)(w + o); o += 16;
    int* done2   = (int*)(w + o); o += 16;
    const size_t zero_elems = o;
    // ---- non-zeroed region ----
    float* h1    = w + o; o += N_NODES * HID;
    float* h2    = w + o; o += N_NODES * OUT_CH;
    float* xs1   = w + o; o += HID * SP;
    float* ys1   = w + o; o += HID * SP;
    float* zs1   = w + o; o += HID * SP;
    float* xs2   = w + o; o += OUT_CH * SP;
    float* ys2   = w + o; o += OUT_CH * SP;
    float* zs2   = w + o; o += OUT_CH * SP;

    hipMemsetAsync(d_ws, 0, zero_elems * sizeof(float), stream);

    gemm1_kernel<<<N_NODES, 256, 0, stream>>>(x, W1, b1, ei, h1, cdeg, srcCnt);

    // ---- layer 1 ----  (32 te blocks/channel; agg fused into te last block)
    sortfill_kernel<HID, false><<<HID, 512, 0, stream>>>(
        h1, srcCnt, ei, nullptr, nullptr, nullptr, nullptr, nullptr, xs1, ys1, zs1);
    te_kernel<HID><<<32 * HID, 1024, 0, stream>>>(
        xs1, ys1, zs1, h1, ei, 1.0f, tes1, sums1, done1);

    // ---- layer 2 ----  (h2 computed inside sortfill; 72 te blocks/channel)
    sortfill_kernel<OUT_CH, true><<<OUT_CH, 512, 0, stream>>>(
        nullptr, srcCnt, ei, sums1, cdeg, W2, b2, h2, xs2, ys2, zs2);
    te_kernel<OUT_CH><<<72 * OUT_CH, 1024, 0, stream>>>(
        xs2, ys2, zs2, h2, ei, 0.5f, tes2, sums2, done2);
    fin2_kernel<<<(N_NODES + 255) / 256, 256, 0, stream>>>(sums2, cdeg, out);
}

// Round 11
// 209.894 us; speedup vs baseline: 1.3263x; 1.3263x over previous
//
#include <hip/hip_runtime.h>
#include <math.h>
#include <float.h>

#define N_NODES 1024
#define IN_CH   1433
#define HID     16
#define OUT_CH  7
#define N_EDGES 4096
#define E_TOT   5120   // N_EDGES + N_NODES (self loops)
#define N_TE    5119   // embedded series length (valid sorted slots 0..5118)
#define SP      5120   // pitch for per-channel sorted arrays

// psi(x) for integer-valued x >= 1. Recurrence to x>=6 then asymptotic.
// digammaf_dev(0) = -inf, matching jax digamma(0) for the degenerate eps==0 case.
__device__ __forceinline__ float digammaf_dev(float x) {
    float r = 0.0f;
    while (x < 6.0f) { r -= 1.0f / x; x += 1.0f; }
    float inv  = 1.0f / x;
    float inv2 = inv * inv;
    r += logf(x) - 0.5f * inv
       - inv2 * (1.0f/12.0f - inv2 * (1.0f/120.0f - inv2 * (1.0f/252.0f)));
    return r;
}

// h1[r][o] = sum_k x[r][k] * W1[o][k] + b1[o].  One block per row.
// Fused: degree count (cdeg) + src multiplicity (srcCnt): 5 edges per block.
__global__ __launch_bounds__(256) void gemm1_kernel(
    const float* __restrict__ x, const float* __restrict__ W1,
    const float* __restrict__ b1, const int* __restrict__ ei,
    float* __restrict__ h1, float* __restrict__ cdeg, int* __restrict__ srcCnt) {
    __shared__ float xrow[IN_CH];
    const int r = blockIdx.x;
    if (threadIdx.x < 5) {            // E_TOT = 5 * N_NODES exactly
        int e = r * 5 + threadIdx.x;
        int d = (e < N_EDGES) ? ei[N_EDGES + e] : (e - N_EDGES);
        atomicAdd(&cdeg[d], 1.0f);
        if (e < N_TE) {
            int s = (e < N_EDGES) ? ei[e] : (e - N_EDGES);
            atomicAdd(&srcCnt[s], 1);
        }
    }
    const float* xr = x + (size_t)r * IN_CH;
    for (int k = threadIdx.x; k < IN_CH; k += 256) xrow[k] = xr[k];
    __syncthreads();
    const int o = threadIdx.x >> 4;
    const int g = threadIdx.x & 15;
    const float* w = W1 + o * IN_CH;
    float s = 0.0f;
    for (int k = g; k < IN_CH; k += 16) s += xrow[k] * w[k];
    #pragma unroll
    for (int m = 8; m >= 1; m >>= 1) s += __shfl_xor(s, m, 16);
    if (g == 0) h1[r * HID + o] = s + b1[o];
}

// Per channel c (one block, 512 threads): bitonic-sort the 1024 node values
// (key=float as sortable uint, payload=node idx); rank/cursor/value tables in
// LDS; then counting-sort scatter of the 5119 embedded points into their
// y-sorted slots. Order inside equal-y groups arbitrary (results
// order-independent: min and window membership are y-value-determined).
// FUSE=false: values come from h[:, c] (layer 1).
// FUSE=true:  values are computed in-block as layer-2 pre-activations
//             h2[v][c] = b2[c] + sum_k relu(sums1[v][k]/deg) * W2[c][k]
//             (byte-identical float expressions to the old fin1gemm2),
//             and also written to h2out for the agg step.
template <int C, bool FUSE>
__global__ __launch_bounds__(512) void sortfill_kernel(
    const float* __restrict__ hin, const int* __restrict__ srcCnt,
    const int* __restrict__ ei,
    const float* __restrict__ sums1, const float* __restrict__ cdeg,
    const float* __restrict__ W2, const float* __restrict__ b2,
    float* __restrict__ h2out,
    float* __restrict__ xs, float* __restrict__ ys, float* __restrict__ zs) {
    __shared__ unsigned long long a[N_NODES];
    __shared__ float hv[N_NODES];
    __shared__ int rankL[N_NODES];
    __shared__ int curL[N_NODES];
    __shared__ int wsum[8];
    const int c = blockIdx.x;
    const int tid = threadIdx.x;
    for (int v = tid; v < N_NODES; v += 512) {
        float f;
        if constexpr (FUSE) {
            float invc = 1.0f / fmaxf(cdeg[v], 1.0f);
            float s = b2[c];
            #pragma unroll
            for (int k = 0; k < HID; ++k)
                s += fmaxf(sums1[v * HID + k] * invc, 0.0f) * W2[c * HID + k];
            f = s;
            h2out[v * C + c] = s;
        } else {
            f = hin[v * C + c];
        }
        hv[v] = f;
        unsigned u = __float_as_uint(f);
        u ^= (u & 0x80000000u) ? 0xFFFFFFFFu : 0x80000000u;
        a[v] = ((unsigned long long)u << 32) | (unsigned)v;
    }
    __syncthreads();
    for (int k = 2; k <= N_NODES; k <<= 1) {
        for (int j = k >> 1; j >= 1; j >>= 1) {
            {   // 512 threads <-> 512 compare-exchanges per substage
                int s = tid;
                int i  = ((s & ~(j - 1)) << 1) | (s & (j - 1));
                int p2 = i | j;
                unsigned long long A = a[i], B = a[p2];
                bool up = ((i & k) == 0);
                if ((A > B) == up) { a[i] = B; a[p2] = A; }
            }
            __syncthreads();
        }
    }
    // ranks + exclusive prefix sum of src multiplicities in sorted order
    const int r0 = tid * 2;
    int n0 = (int)(a[r0]     & 0xFFFFFFFFu);
    int n1 = (int)(a[r0 + 1] & 0xFFFFFFFFu);
    rankL[n0] = r0;
    rankL[n1] = r0 + 1;
    int c0 = srcCnt[n0], c1 = srcCnt[n1];
    int seg = c0 + c1;
    int run = seg;
    const int lane = tid & 63, wid = tid >> 6;
    #pragma unroll
    for (int m = 1; m < 64; m <<= 1) {
        int v = __shfl_up(run, m, 64);
        if (lane >= m) run += v;
    }
    if (lane == 63) wsum[wid] = run;
    __syncthreads();
    int base = 0;
    for (int ww = 0; ww < wid; ++ww) base += wsum[ww];
    int excl = base + run - seg;
    curL[r0]     = excl;
    curL[r0 + 1] = excl + c0;
    __syncthreads();
    // counting-sort scatter (cursor atomics in LDS; h values from LDS)
    for (int t = tid; t < N_TE; t += 512) {
        int s  = (t < N_EDGES)     ? ei[t]     : t - N_EDGES;
        int sn = (t + 1 < N_EDGES) ? ei[t + 1] : t + 1 - N_EDGES;
        int d  = (t < N_EDGES) ? ei[N_EDGES + t] : t - N_EDGES;
        int pos = atomicAdd(&curL[rankL[s]], 1);
        ys[c * SP + pos] = hv[s];
        xs[c * SP + pos] = hv[d];
        zs[c * SP + pos] = hv[sn];
    }
}

// Fused KSG: ONE 64-lane wave per point p (sorted position). Grid =
// nb blocks/channel (nb = gridDim.x / C); block (c, b_local) owns the point
// set {p = i*nb + b_local} — stride-nb interleave decorrelates the regional
// clustering of heavy-window points. Waves pull i from an LDS cursor
// (block-local atomic; r8 lesson: one global cursor serializes the whole
// machine; r10 lesson: cross-block rendezvous/agg tails inside this kernel
// expose the tail and perturb codegen). Loop bodies identical to r7/r9
// (r6 lesson: perturbing the load pattern costs LDS conflicts).
//   eps phase:   per-lane running best; break when ANY lane has dyB >= best_l
//                — exactly dyB >= wave-min(best), the optimal exact stop.
//                Overshoot-safe (d >= |dy|).
//   left loops:  pre-tested on the candidate round's top y: failing rounds are
//                provably non-contributing and skipped without processing.
//   count phase: window predicates via ballot+popcount; counts in SGPRs.
//                Right scan owns the base round, left scan strictly below:
//                no side masks; self pair IS the +1-inside-psi convention.
//                eps<=0 short-circuits to counts 0 -> digamma(0) = -inf,
//                matching the reference degenerate case.
// Sentinels: left pad -FLT_MAX, right pad / slot N_TE +FLT_MAX.
template <int C>
__global__ __launch_bounds__(1024, 4) void te_kernel(
    const float* __restrict__ xs, const float* __restrict__ ys,
    const float* __restrict__ zs, float* __restrict__ tes) {
    constexpr int LOFF = 512;            // left pad
    constexpr int LSZ  = 5888;           // LOFF + SP + 256 (covers prefetch)
    __shared__ __align__(16) float Xs[LSZ];
    __shared__ __align__(16) float Ys[LSZ];
    __shared__ __align__(16) float Zs[LSZ];
    __shared__ int lcur;
    const int nb = gridDim.x / C;        // blocks per channel
    const int c = blockIdx.x / nb;
    const int b_local = blockIdx.x % nb;
    const int tid = threadIdx.x;
    {
        const float4* gx4 = (const float4*)(xs + (size_t)c * SP);
        const float4* gy4 = (const float4*)(ys + (size_t)c * SP);
        const float4* gz4 = (const float4*)(zs + (size_t)c * SP);
        float4* lx4 = (float4*)(Xs + LOFF);
        float4* ly4 = (float4*)(Ys + LOFF);
        float4* lz4 = (float4*)(Zs + LOFF);
        for (int t = tid; t < SP / 4; t += 1024) {
            lx4[t] = gx4[t]; ly4[t] = gy4[t]; lz4[t] = gz4[t];
        }
        for (int t = tid; t < LOFF; t += 1024) {
            Xs[t] = -FLT_MAX; Ys[t] = -FLT_MAX; Zs[t] = -FLT_MAX;
        }
        for (int t = LOFF + SP + tid; t < LSZ; t += 1024) {
            Xs[t] = FLT_MAX; Ys[t] = FLT_MAX; Zs[t] = FLT_MAX;
        }
    }
    __syncthreads();
    if (tid == 0) {  // slot N_TE holds fill garbage; make it a sentinel
        Xs[LOFF + N_TE] = FLT_MAX; Ys[LOFF + N_TE] = FLT_MAX; Zs[LOFF + N_TE] = FLT_MAX;
        lcur = 0;
    }
    __syncthreads();

    const int wv = tid >> 6, l = tid & 63;
    float accum = 0.0f;

#define LD4(arr, idx) (*(const float4*)((arr) + LOFF + (idx)))
#define TE_D(xc, yc, zc) \
    fmaxf(fmaxf(fabsf((xc) - xi), fabsf((yc) - yi)), fabsf((zc) - zi))

    while (true) {
        int i = 0;
        if (l == 0) i = atomicAdd(&lcur, 1);
        i = __shfl(i, 0, 64);
        const int p = i * nb + b_local;
        if (p >= N_TE) break;

        const float xi = Xs[LOFF + p], yi = Ys[LOFF + p], zi = Zs[LOFF + p];
        const int base = p & ~255;
        const int lo4 = l * 4;

        float best = FLT_MAX;
        // ---- eps: right/up (includes base round; j==p masked; prefetched) --
        {
            int b = base;
            float4 x0 = LD4(Xs, b + lo4), y0 = LD4(Ys, b + lo4), z0 = LD4(Zs, b + lo4);
            float yB0 = Ys[LOFF + b + 255];
            while (true) {
                float4 x1 = LD4(Xs, b + 256 + lo4);
                float4 y1 = LD4(Ys, b + 256 + lo4);
                float4 z1 = LD4(Zs, b + 256 + lo4);
                float yB1 = Ys[LOFF + b + 511];
                const int j0 = b + lo4;
                float d0 = TE_D(x0.x, y0.x, z0.x);
                float d1 = TE_D(x0.y, y0.y, z0.y);
                float d2 = TE_D(x0.z, y0.z, z0.z);
                float d3 = TE_D(x0.w, y0.w, z0.w);
                d0 = (j0     == p) ? FLT_MAX : d0;
                d1 = (j0 + 1 == p) ? FLT_MAX : d1;
                d2 = (j0 + 2 == p) ? FLT_MAX : d2;
                d3 = (j0 + 3 == p) ? FLT_MAX : d3;
                best = fminf(fminf(best, d0), fminf(fminf(d1, d2), d3));
                if (__ballot(yB0 - yi >= best) != 0ull) break;   // wave-min stop
                x0 = x1; y0 = y1; z0 = z1; yB0 = yB1; b += 256;
            }
        }
        // ---- eps: left/down, pre-tested on candidate round's top y ----
        {
            int b = base - 256;
            while (__ballot(yi - Ys[LOFF + b + 255] >= best) == 0ull) {
                float4 x0 = LD4(Xs, b + lo4), y0 = LD4(Ys, b + lo4), z0 = LD4(Zs, b + lo4);
                float d0 = TE_D(x0.x, y0.x, z0.x);
                float d1 = TE_D(x0.y, y0.y, z0.y);
                float d2 = TE_D(x0.z, y0.z, z0.z);
                float d3 = TE_D(x0.w, y0.w, z0.w);
                best = fminf(fminf(best, d0), fminf(fminf(d1, d2), d3));
                b -= 256;
            }
        }
        #pragma unroll
        for (int m = 1; m < 64; m <<= 1) best = fminf(best, __shfl_xor(best, m, 64));
        const float eps = best;

        int ny = 0, nxy = 0, nyz = 0;
        if (eps > 0.0f) {
#define TE_CSLOT(xc, yc, zc)                                                 \
    {                                                                        \
        unsigned long long my_ = __ballot(fabsf((yc) - yi) < eps);           \
        unsigned long long mx_ = __ballot(fabsf((xc) - xi) < eps);           \
        unsigned long long mz_ = __ballot(fabsf((zc) - zi) < eps);           \
        ny  += __popcll(my_);                                                \
        nxy += __popcll(my_ & mx_);                                          \
        nyz += __popcll(my_ & mz_);                                          \
    }
            // ---- count: right (whole base round + up; self included) ----
            {
                int b = base;
                float4 x0 = LD4(Xs, b + lo4), y0 = LD4(Ys, b + lo4), z0 = LD4(Zs, b + lo4);
                float yB0 = Ys[LOFF + b + 255];
                while (true) {
                    float4 x1 = LD4(Xs, b + 256 + lo4);
                    float4 y1 = LD4(Ys, b + 256 + lo4);
                    float4 z1 = LD4(Zs, b + 256 + lo4);
                    float yB1 = Ys[LOFF + b + 511];
                    TE_CSLOT(x0.x, y0.x, z0.x)
                    TE_CSLOT(x0.y, y0.y, z0.y)
                    TE_CSLOT(x0.z, y0.z, z0.z)
                    TE_CSLOT(x0.w, y0.w, z0.w)
                    if (yB0 - yi >= eps) break;      // uniform: window covered
                    x0 = x1; y0 = y1; z0 = z1; yB0 = yB1; b += 256;
                }
            }
            // ---- count: left, pre-tested on candidate round's top y ----
            {
                int b = base - 256;
                while (yi - Ys[LOFF + b + 255] < eps) {   // uniform
                    float4 x0 = LD4(Xs, b + lo4), y0 = LD4(Ys, b + lo4), z0 = LD4(Zs, b + lo4);
                    TE_CSLOT(x0.x, y0.x, z0.x)
                    TE_CSLOT(x0.y, y0.y, z0.y)
                    TE_CSLOT(x0.z, y0.z, z0.z)
                    TE_CSLOT(x0.w, y0.w, z0.w)
                    b -= 256;
                }
            }
#undef TE_CSLOT
        }
        if (l == 0)
            accum += digammaf_dev((float)ny) - digammaf_dev((float)nxy)
                   - digammaf_dev((float)nyz);
    }
#undef LD4
#undef TE_D

    __shared__ float wred[16];
    if (l == 0) wred[wv] = accum;
    __syncthreads();
    if (tid == 0) {
        float s = 0.0f;
        #pragma unroll
        for (int i = 0; i < 16; ++i) s += wred[i];
        atomicAdd(&tes[c], s);
    }
}

// msg = sigmoid(te_c * h[src][c]); segment-sum into sums[dst][c]
template <int C>
__global__ void agg_kernel(const float* __restrict__ h, const int* __restrict__ ei,
                           const float* __restrict__ tes_accum, float half_scale,
                           float* __restrict__ sums) {
    int idx = blockIdx.x * blockDim.x + threadIdx.x;
    if (idx >= E_TOT * C) return;
    int e = idx / C, c = idx % C;
    int s = (e < N_EDGES) ? ei[e] : (e - N_EDGES);
    int d = (e < N_EDGES) ? ei[N_EDGES + e] : (e - N_EDGES);
    float te = (-0.57721566490153286f + tes_accum[c] * (1.0f / (float)N_TE)) * half_scale;
    float xj = h[s * C + c];
    float m = 1.0f / (1.0f + expf(-te * xj));
    atomicAdd(&sums[d * C + c], m);
}

__global__ void fin2_kernel(const float* __restrict__ sums2, const float* __restrict__ cnt,
                            float* __restrict__ out) {
    int v = blockIdx.x * blockDim.x + threadIdx.x;
    if (v >= N_NODES) return;
    float c = fmaxf(cnt[v], 1.0f);
    float vals[OUT_CH];
    float mx = -INFINITY;
    #pragma unroll
    for (int o = 0; o < OUT_CH; ++o) {
        vals[o] = sums2[v * OUT_CH + o] / c;
        mx = fmaxf(mx, vals[o]);
    }
    float se = 0.0f;
    #pragma unroll
    for (int o = 0; o < OUT_CH; ++o) se += expf(vals[o] - mx);
    float lse = mx + logf(se);
    #pragma unroll
    for (int o = 0; o < OUT_CH; ++o) out[v * OUT_CH + o] = vals[o] - lse;
}

extern "C" void kernel_launch(void* const* d_in, const int* in_sizes, int n_in,
                              void* d_out, int out_size, void* d_ws, size_t ws_size,
                              hipStream_t stream) {
    const float* x  = (const float*)d_in[0];
    const int*   ei = (const int*)  d_in[1];
    const float* W1 = (const float*)d_in[2];
    const float* b1 = (const float*)d_in[3];
    const float* W2 = (const float*)d_in[4];
    const float* b2 = (const float*)d_in[5];
    float* out = (float*)d_out;

    float* w = (float*)d_ws;
    size_t o = 0;
    // ---- zeroed region (atomic accumulators) ----
    float* sums1 = w + o; o += N_NODES * HID;      // 16384
    float* sums2 = w + o; o += N_NODES * OUT_CH;   // 7168
    float* cdeg  = w + o; o += N_NODES;            // 1024
    float* tes1  = w + o; o += 16;
    float* tes2  = w + o; o += 16;
    int* srcCnt  = (int*)(w + o); o += N_NODES;    // 1024 ints
    const size_t zero_elems = o;
    // ---- non-zeroed region ----
    float* h1    = w + o; o += N_NODES * HID;
    float* h2    = w + o; o += N_NODES * OUT_CH;
    float* xs1   = w + o; o += HID * SP;
    float* ys1   = w + o; o += HID * SP;
    float* zs1   = w + o; o += HID * SP;
    float* xs2   = w + o; o += OUT_CH * SP;
    float* ys2   = w + o; o += OUT_CH * SP;
    float* zs2   = w + o; o += OUT_CH * SP;

    hipMemsetAsync(d_ws, 0, zero_elems * sizeof(float), stream);

    gemm1_kernel<<<N_NODES, 256, 0, stream>>>(x, W1, b1, ei, h1, cdeg, srcCnt);

    // ---- layer 1 ----  (32 te blocks/channel)
    sortfill_kernel<HID, false><<<HID, 512, 0, stream>>>(
        h1, srcCnt, ei, nullptr, nullptr, nullptr, nullptr, nullptr, xs1, ys1, zs1);
    te_kernel<HID><<<32 * HID, 1024, 0, stream>>>(xs1, ys1, zs1, tes1);
    agg_kernel<HID><<<(E_TOT * HID + 255) / 256, 256, 0, stream>>>(h1, ei, tes1, 1.0f, sums1);

    // ---- layer 2 ----  (h2 computed inside sortfill; 72 te blocks/channel)
    sortfill_kernel<OUT_CH, true><<<OUT_CH, 512, 0, stream>>>(
        nullptr, srcCnt, ei, sums1, cdeg, W2, b2, h2, xs2, ys2, zs2);
    te_kernel<OUT_CH><<<72 * OUT_CH, 1024, 0, stream>>>(xs2, ys2, zs2, tes2);
    agg_kernel<OUT_CH><<<(E_TOT * OUT_CH + 255) / 256, 256, 0, stream>>>(h2, ei, tes2, 0.5f, sums2);
    fin2_kernel<<<(N_NODES + 255) / 256, 256, 0, stream>>>(sums2, cdeg, out);
}